// Round 1
// baseline (613.558 us; speedup 1.0000x reference)
//
#include <hip/hip_runtime.h>
#include <hip/hip_bf16.h>
#include <math.h>

#define NN 50000
#define NE 800000
#define DD 128
#define NCLS 10
#define SCAN_BLOCK 1024
#define NTILES ((NN + 1 + SCAN_BLOCK - 1) / SCAN_BLOCK)  // 49

// ---- monotonic float<->uint key for atomic max over floats (incl. negatives) ----
__device__ __forceinline__ unsigned int fkey(float f) {
  unsigned int u = __float_as_uint(f);
  return u ^ ((u & 0x80000000u) ? 0xFFFFFFFFu : 0x80000000u);
}
__device__ __forceinline__ float funkey(unsigned int k) {
  unsigned int u = (k & 0x80000000u) ? (k ^ 0x80000000u) : ~k;
  return __uint_as_float(u);
}

// ---- init: zero counts and column-max keys (ws is poisoned 0xAA every call) ----
__global__ void k_init(int* __restrict__ offs, unsigned int* __restrict__ omax) {
  int i = blockIdx.x * blockDim.x + threadIdx.x;
  if (i < NN + 1) offs[i] = 0;
  if (i < 3 * DD) omax[i] = 0u;  // key 0 == "minimum"
}

// ---- CSR build ----
__global__ void k_count(const int* __restrict__ edst, int* __restrict__ offs) {
  int e = blockIdx.x * blockDim.x + threadIdx.x;
  if (e < NE) atomicAdd(&offs[edst[e] + 1], 1);
}

__global__ void k_scan_partial(const int* __restrict__ offs, int* __restrict__ bsum) {
  __shared__ int red[SCAN_BLOCK];
  int i = blockIdx.x * SCAN_BLOCK + threadIdx.x;
  red[threadIdx.x] = (i < NN + 1) ? offs[i] : 0;
  __syncthreads();
  for (int off = SCAN_BLOCK / 2; off > 0; off >>= 1) {
    if ((int)threadIdx.x < off) red[threadIdx.x] += red[threadIdx.x + off];
    __syncthreads();
  }
  if (threadIdx.x == 0) bsum[blockIdx.x] = red[0];
}

__global__ void k_scan_bsum(int* __restrict__ bsum) {
  if (threadIdx.x == 0) {
    int run = 0;
    for (int i = 0; i < NTILES; ++i) { int v = bsum[i]; bsum[i] = run; run += v; }
  }
}

__global__ void k_scan_final(int* __restrict__ offs, const int* __restrict__ bsum,
                             int* __restrict__ cursor) {
  __shared__ int tmp[SCAN_BLOCK];
  int i = blockIdx.x * SCAN_BLOCK + threadIdx.x;
  int v = (i < NN + 1) ? offs[i] : 0;
  tmp[threadIdx.x] = v;
  __syncthreads();
  for (int off = 1; off < SCAN_BLOCK; off <<= 1) {
    int t = ((int)threadIdx.x >= off) ? tmp[threadIdx.x - off] : 0;
    __syncthreads();
    tmp[threadIdx.x] += t;
    __syncthreads();
  }
  int incl = tmp[threadIdx.x] + bsum[blockIdx.x];
  if (i < NN + 1) {
    offs[i] = incl;              // offs[d] = start of node d, offs[NN] = NE
    if (i < NN) cursor[i] = incl;
  }
}

__global__ void k_fill(const int* __restrict__ esrc, const int* __restrict__ edst,
                       const float* __restrict__ ew, int* __restrict__ cursor,
                       int2* __restrict__ csr) {
  int e = blockIdx.x * blockDim.x + threadIdx.x;
  if (e < NE) {
    int d = edst[e];
    int p = atomicAdd(&cursor[d], 1);
    csr[p] = make_int2(esrc[e], __float_as_int(ew[e]));
  }
}

// ---- GEMM: S[N,128] = H[N,128] @ W[128,128]; W fully in LDS ----
// block=256 (4 waves); each wave computes 8 rows x 128 cols (2 cols/lane).
__global__ __launch_bounds__(256) void k_gemm(const float* __restrict__ H,
                                              const float* __restrict__ Wm,
                                              float* __restrict__ S) {
  __shared__ float Wl[DD * DD];      // 64 KB
  __shared__ float Hl[4][8][DD];     // 16 KB
  {
    const float4* wv = (const float4*)Wm;
    float4* lv = (float4*)Wl;
#pragma unroll
    for (int i = 0; i < (DD * DD / 4) / 256; ++i)
      lv[i * 256 + threadIdx.x] = wv[i * 256 + threadIdx.x];
  }
  __syncthreads();
  const int wave = threadIdx.x >> 6;
  const int lane = threadIdx.x & 63;
  const int c0 = lane * 2;
  const int ngroups = (NN + 31) / 32;
  for (int g = blockIdx.x; g < ngroups; g += gridDim.x) {
    const int r0 = g * 32 + wave * 8;
    // stage this wave's 8 rows (lanes 0-31 row 2p, lanes 32-63 row 2p+1)
#pragma unroll
    for (int p = 0; p < 4; ++p) {
      int rr = p * 2 + (lane >> 5);
      int r = r0 + rr;
      int c4 = lane & 31;
      float4 v = make_float4(0.f, 0.f, 0.f, 0.f);
      if (r < NN) v = ((const float4*)(H + (size_t)r * DD))[c4];
      ((float4*)Hl[wave][rr])[c4] = v;
    }
    __syncthreads();
    float2 acc[8];
#pragma unroll
    for (int i = 0; i < 8; ++i) acc[i] = make_float2(0.f, 0.f);
    for (int k = 0; k < DD; k += 4) {
      float2 w0 = *(const float2*)&Wl[(k + 0) * DD + c0];
      float2 w1 = *(const float2*)&Wl[(k + 1) * DD + c0];
      float2 w2 = *(const float2*)&Wl[(k + 2) * DD + c0];
      float2 w3 = *(const float2*)&Wl[(k + 3) * DD + c0];
#pragma unroll
      for (int i = 0; i < 8; ++i) {
        float4 h4 = *(const float4*)&Hl[wave][i][k];
        float ax = acc[i].x, ay = acc[i].y;
        ax = fmaf(h4.x, w0.x, ax); ay = fmaf(h4.x, w0.y, ay);
        ax = fmaf(h4.y, w1.x, ax); ay = fmaf(h4.y, w1.y, ay);
        ax = fmaf(h4.z, w2.x, ax); ay = fmaf(h4.z, w2.y, ay);
        ax = fmaf(h4.w, w3.x, ax); ay = fmaf(h4.w, w3.y, ay);
        acc[i].x = ax; acc[i].y = ay;
      }
    }
#pragma unroll
    for (int i = 0; i < 8; ++i) {
      int r = r0 + i;
      if (r < NN) *(float2*)&S[(size_t)r * DD + c0] = acc[i];
    }
    __syncthreads();
  }
}

// ---- aggregation: X[d] = (relu)( b + sum_e w_e * S[src_e] ), fused column max ----
// one wave per node, 2 cols/lane; grid-stride over nodes.
__global__ __launch_bounds__(256) void k_agg(const float* __restrict__ S,
                                             const int2* __restrict__ csr,
                                             const int* __restrict__ offs,
                                             const float* __restrict__ bias,
                                             float* __restrict__ Xout,  // may be null
                                             unsigned int* __restrict__ omax,
                                             int do_relu) {
  __shared__ unsigned int cmax[DD];
  for (int i = threadIdx.x; i < DD; i += 256) cmax[i] = 0u;
  __syncthreads();
  const int lane = threadIdx.x & 63;
  const int wave = threadIdx.x >> 6;
  const int gwave = blockIdx.x * 4 + wave;
  const int nwaves = gridDim.x * 4;
  const int c0 = lane * 2;
  const float2 b2 = *(const float2*)&bias[c0];
  float2 mx = make_float2(-INFINITY, -INFINITY);
  for (int d = gwave; d < NN; d += nwaves) {
    const int e1 = offs[d + 1];
    float2 acc = b2;
    for (int e = offs[d]; e < e1; ++e) {
      int2 sw = csr[e];                       // broadcast 8B
      float w = __int_as_float(sw.y);
      float2 s2 = *(const float2*)&S[(size_t)sw.x * DD + c0];
      acc.x = fmaf(w, s2.x, acc.x);
      acc.y = fmaf(w, s2.y, acc.y);
    }
    if (do_relu) { acc.x = fmaxf(acc.x, 0.f); acc.y = fmaxf(acc.y, 0.f); }
    if (Xout) *(float2*)&Xout[(size_t)d * DD + c0] = acc;
    mx.x = fmaxf(mx.x, acc.x);
    mx.y = fmaxf(mx.y, acc.y);
  }
  atomicMax(&cmax[c0], fkey(mx.x));
  atomicMax(&cmax[c0 + 1], fkey(mx.y));
  __syncthreads();
  for (int i = threadIdx.x; i < DD; i += 256) atomicMax(&omax[i], cmax[i]);
}

// ---- head: decode column maxes, logits = lin_W @ o + lin_b, log_softmax ----
__global__ void k_head(const unsigned int* __restrict__ omax,
                       const float* __restrict__ linW,
                       const float* __restrict__ linb,
                       float* __restrict__ out) {
  __shared__ float o[3 * DD];
  __shared__ float logits[NCLS];
  int t = threadIdx.x;  // block = 384
  if (t < 3 * DD) o[t] = funkey(omax[t]);
  __syncthreads();
  if (t < NCLS) {
    float acc = linb[t];
    for (int j = 0; j < 3 * DD; ++j) acc = fmaf(linW[t * 3 * DD + j], o[j], acc);
    logits[t] = acc;
  }
  __syncthreads();
  if (t == 0) {
    float m = -INFINITY;
    for (int c = 0; c < NCLS; ++c) m = fmaxf(m, logits[c]);
    float s = 0.f;
    for (int c = 0; c < NCLS; ++c) s += expf(logits[c] - m);
    float ls = logf(s);
    for (int c = 0; c < NCLS; ++c) out[c] = logits[c] - m - ls;
  }
}

extern "C" void kernel_launch(void* const* d_in, const int* in_sizes, int n_in,
                              void* d_out, int out_size, void* d_ws, size_t ws_size,
                              hipStream_t stream) {
  const float* x    = (const float*)d_in[0];
  const int*   esrc = (const int*)d_in[1];
  const int*   edst = (const int*)d_in[2];
  const float* ew   = (const float*)d_in[3];
  const float* W1   = (const float*)d_in[4];
  const float* b1   = (const float*)d_in[5];
  const float* W2   = (const float*)d_in[6];
  const float* b2   = (const float*)d_in[7];
  const float* W3   = (const float*)d_in[8];
  const float* b3   = (const float*)d_in[9];
  const float* linW = (const float*)d_in[10];
  const float* linb = (const float*)d_in[11];
  float* out = (float*)d_out;

  size_t off = 0;
  auto alloc = [&](size_t bytes) {
    void* p = (char*)d_ws + off;
    off += (bytes + 255) & ~(size_t)255;
    return p;
  };
  float*        S      = (float*)alloc((size_t)NN * DD * 4);
  float*        X      = (float*)alloc((size_t)NN * DD * 4);
  int*          offs   = (int*)alloc((NN + 1) * 4);
  int*          cursor = (int*)alloc(NN * 4);
  int2*         csr    = (int2*)alloc((size_t)NE * 8);
  unsigned int* omax   = (unsigned int*)alloc(3 * DD * 4);
  int*          bsum   = (int*)alloc(NTILES * 4);
  (void)ws_size; (void)n_in; (void)in_sizes; (void)out_size;

  // CSR build (once; shared by all 3 layers)
  k_init<<<(NN + 256) / 256, 256, 0, stream>>>(offs, omax);
  k_count<<<(NE + 255) / 256, 256, 0, stream>>>(edst, offs);
  k_scan_partial<<<NTILES, SCAN_BLOCK, 0, stream>>>(offs, bsum);
  k_scan_bsum<<<1, 64, 0, stream>>>(bsum);
  k_scan_final<<<NTILES, SCAN_BLOCK, 0, stream>>>(offs, bsum, cursor);
  k_fill<<<(NE + 255) / 256, 256, 0, stream>>>(esrc, edst, ew, cursor, csr);

  // layer 1: S = x@W1 ; X = relu(agg(S)+b1), o1
  k_gemm<<<512, 256, 0, stream>>>(x, W1, S);
  k_agg<<<2048, 256, 0, stream>>>(S, csr, offs, b1, X, omax, 1);
  // layer 2: S = X@W2 ; X = relu(agg(S)+b2), o2
  k_gemm<<<512, 256, 0, stream>>>(X, W2, S);
  k_agg<<<2048, 256, 0, stream>>>(S, csr, offs, b2, X, omax + DD, 1);
  // layer 3: S = X@W3 ; o3 only (no store, no relu)
  k_gemm<<<512, 256, 0, stream>>>(X, W3, S);
  k_agg<<<2048, 256, 0, stream>>>(S, csr, offs, b3, nullptr, omax + 2 * DD, 0);

  k_head<<<1, 384, 0, stream>>>(omax, linW, linb, out);
}

// Round 2
// 440.544 us; speedup vs baseline: 1.3927x; 1.3927x over previous
//
#include <hip/hip_runtime.h>
#include <hip/hip_bf16.h>
#include <math.h>

#define NN 50000
#define NPAD 50048            // 782 chunks of 64 rows
#define NE 800000
#define DD 128
#define NCLS 10
#define SCAN_BLOCK 1024
#define NTILES ((NN + 1 + SCAN_BLOCK - 1) / SCAN_BLOCK)  // 49

typedef short s16x8 __attribute__((ext_vector_type(8)));
typedef float f32x4 __attribute__((ext_vector_type(4)));

__device__ __forceinline__ unsigned short f2bf(float x) {
  __hip_bfloat16 h = __float2bfloat16(x);
  return __builtin_bit_cast(unsigned short, h);
}

// ---- monotonic float<->uint key for atomic max over floats ----
__device__ __forceinline__ unsigned int fkey(float f) {
  unsigned int u = __float_as_uint(f);
  return u ^ ((u & 0x80000000u) ? 0xFFFFFFFFu : 0x80000000u);
}
__device__ __forceinline__ float funkey(unsigned int k) {
  unsigned int u = (k & 0x80000000u) ? (k ^ 0x80000000u) : ~k;
  return __uint_as_float(u);
}

// ---- init ----
__global__ void k_init(int* __restrict__ offs, unsigned int* __restrict__ omax) {
  int i = blockIdx.x * blockDim.x + threadIdx.x;
  if (i < NN + 1) offs[i] = 0;
  if (i < 3 * DD) omax[i] = 0u;
}

// ---- CSR build ----
__global__ void k_count(const int* __restrict__ edst, int* __restrict__ offs) {
  int e = blockIdx.x * blockDim.x + threadIdx.x;
  if (e < NE) atomicAdd(&offs[edst[e] + 1], 1);
}

__global__ void k_scan_partial(const int* __restrict__ offs, int* __restrict__ bsum) {
  __shared__ int red[SCAN_BLOCK];
  int i = blockIdx.x * SCAN_BLOCK + threadIdx.x;
  red[threadIdx.x] = (i < NN + 1) ? offs[i] : 0;
  __syncthreads();
  for (int off = SCAN_BLOCK / 2; off > 0; off >>= 1) {
    if ((int)threadIdx.x < off) red[threadIdx.x] += red[threadIdx.x + off];
    __syncthreads();
  }
  if (threadIdx.x == 0) bsum[blockIdx.x] = red[0];
}

__global__ void k_scan_bsum(int* __restrict__ bsum) {
  if (threadIdx.x == 0) {
    int run = 0;
    for (int i = 0; i < NTILES; ++i) { int v = bsum[i]; bsum[i] = run; run += v; }
  }
}

__global__ void k_scan_final(int* __restrict__ offs, const int* __restrict__ bsum,
                             int* __restrict__ cursor) {
  __shared__ int tmp[SCAN_BLOCK];
  int i = blockIdx.x * SCAN_BLOCK + threadIdx.x;
  int v = (i < NN + 1) ? offs[i] : 0;
  tmp[threadIdx.x] = v;
  __syncthreads();
  for (int off = 1; off < SCAN_BLOCK; off <<= 1) {
    int t = ((int)threadIdx.x >= off) ? tmp[threadIdx.x - off] : 0;
    __syncthreads();
    tmp[threadIdx.x] += t;
    __syncthreads();
  }
  int incl = tmp[threadIdx.x] + bsum[blockIdx.x];
  if (i < NN + 1) {
    offs[i] = incl;
    if (i < NN) cursor[i] = incl;
  }
}

__global__ void k_fill(const int* __restrict__ esrc, const int* __restrict__ edst,
                       const float* __restrict__ ew, int* __restrict__ cursor,
                       int2* __restrict__ csr) {
  int e = blockIdx.x * blockDim.x + threadIdx.x;
  if (e < NE) {
    int d = edst[e];
    int p = atomicAdd(&cursor[d], 1);
    csr[p] = make_int2(esrc[e], __float_as_int(ew[e]));
  }
}

// ---- convert x -> bf16 (padded), W1..3 -> transposed bf16 WT[c][k] ----
__global__ __launch_bounds__(256) void k_cvt(const float* __restrict__ x,
                     const float* __restrict__ W1, const float* __restrict__ W2,
                     const float* __restrict__ W3,
                     unsigned short* __restrict__ HB,
                     unsigned short* __restrict__ WT1, unsigned short* __restrict__ WT2,
                     unsigned short* __restrict__ WT3) {
  const int stride = gridDim.x * 256;
  int i = blockIdx.x * 256 + threadIdx.x;
  const int n4 = NPAD * DD / 4;
  const int nx4 = NN * DD / 4;
  for (int idx = i; idx < n4; idx += stride) {
    float4 v = make_float4(0.f, 0.f, 0.f, 0.f);
    if (idx < nx4) v = ((const float4*)x)[idx];
    ushort2 lo = make_ushort2(f2bf(v.x), f2bf(v.y));
    ushort2 hi = make_ushort2(f2bf(v.z), f2bf(v.w));
    uint2 pv = make_uint2((uint)lo.x | ((uint)lo.y << 16), (uint)hi.x | ((uint)hi.y << 16));
    *(uint2*)&HB[idx * 4] = pv;
  }
  if (i < DD * DD) {
    int k = i >> 7, c = i & 127;
    WT1[c * DD + k] = f2bf(W1[i]);
    WT2[c * DD + k] = f2bf(W2[i]);
    WT3[c * DD + k] = f2bf(W3[i]);
  }
}

// ---- MFMA GEMM: S[r][c] = sum_k H[r][k] W[k][c], all bf16, no LDS ----
// Computed in S^T orientation: A = W^T frags, B = H frags, so C-regs are
// 4 consecutive cols of row-major S -> packed 8B stores.
// wave = 64 rows x 64 cols; gw>>1 selects row-chunk, gw&1 selects col half.
__global__ __launch_bounds__(256) void k_mm(const unsigned short* __restrict__ H,
                                            const unsigned short* __restrict__ Wt,
                                            unsigned short* __restrict__ S) {
  const int wave = threadIdx.x >> 6, lane = threadIdx.x & 63;
  const int gw = blockIdx.x * 4 + wave;
  const int r0 = (gw >> 1) * 64;
  const int cbase = (gw & 1) * 64;
  const int l15 = lane & 15, lk = (lane >> 4) * 8;

  s16x8 Af[4][4];  // [m = c-frag][ks]
  s16x8 Bf[4][4];  // [n = r-frag][ks]
#pragma unroll
  for (int m = 0; m < 4; ++m)
#pragma unroll
    for (int ks = 0; ks < 4; ++ks)
      Af[m][ks] = *(const s16x8*)&Wt[(cbase + m * 16 + l15) * DD + ks * 32 + lk];
#pragma unroll
  for (int n = 0; n < 4; ++n)
#pragma unroll
    for (int ks = 0; ks < 4; ++ks)
      Bf[n][ks] = *(const s16x8*)&H[(size_t)(r0 + n * 16 + l15) * DD + ks * 32 + lk];

  f32x4 acc[4][4];
#pragma unroll
  for (int m = 0; m < 4; ++m)
#pragma unroll
    for (int n = 0; n < 4; ++n) acc[m][n] = (f32x4){0.f, 0.f, 0.f, 0.f};

#pragma unroll
  for (int ks = 0; ks < 4; ++ks)
#pragma unroll
    for (int m = 0; m < 4; ++m)
#pragma unroll
      for (int n = 0; n < 4; ++n)
        acc[m][n] = __builtin_amdgcn_mfma_f32_16x16x32_bf16(Af[m][ks], Bf[n][ks],
                                                            acc[m][n], 0, 0, 0);

  const int csub = 4 * (lane >> 4);
#pragma unroll
  for (int m = 0; m < 4; ++m)
#pragma unroll
    for (int n = 0; n < 4; ++n) {
      uint2 pv;
      pv.x = (uint)f2bf(acc[m][n][0]) | ((uint)f2bf(acc[m][n][1]) << 16);
      pv.y = (uint)f2bf(acc[m][n][2]) | ((uint)f2bf(acc[m][n][3]) << 16);
      *(uint2*)&S[(size_t)(r0 + n * 16 + l15) * DD + cbase + m * 16 + csub] = pv;
    }
}

// ---- aggregation over bf16 S, fp32 accumulate, bf16 X out, fused col-max ----
__global__ __launch_bounds__(256) void k_agg(const unsigned short* __restrict__ S,
                                             const int2* __restrict__ csr,
                                             const int* __restrict__ offs,
                                             const float* __restrict__ bias,
                                             unsigned short* __restrict__ Xout,  // may be null
                                             unsigned int* __restrict__ omax,
                                             int do_relu) {
  __shared__ unsigned int cmax[DD];
  for (int i = threadIdx.x; i < DD; i += 256) cmax[i] = 0u;
  __syncthreads();
  const int lane = threadIdx.x & 63;
  const int wave = threadIdx.x >> 6;
  const int gwave = blockIdx.x * 4 + wave;
  const int nwaves = gridDim.x * 4;
  const int c0 = lane * 2;
  const float2 b2 = *(const float2*)&bias[c0];
  float2 mx = make_float2(-INFINITY, -INFINITY);
  for (int d = gwave; d < NN; d += nwaves) {
    const int e1 = offs[d + 1];
    int e = offs[d];
    float2 acc = b2;
    for (; e + 4 <= e1; e += 4) {
      int2 sw0 = csr[e + 0];
      int2 sw1 = csr[e + 1];
      int2 sw2 = csr[e + 2];
      int2 sw3 = csr[e + 3];
      unsigned int u0 = *(const unsigned int*)&S[(size_t)sw0.x * DD + c0];
      unsigned int u1 = *(const unsigned int*)&S[(size_t)sw1.x * DD + c0];
      unsigned int u2 = *(const unsigned int*)&S[(size_t)sw2.x * DD + c0];
      unsigned int u3 = *(const unsigned int*)&S[(size_t)sw3.x * DD + c0];
      float w0 = __int_as_float(sw0.y), w1 = __int_as_float(sw1.y);
      float w2 = __int_as_float(sw2.y), w3 = __int_as_float(sw3.y);
      acc.x = fmaf(w0, __uint_as_float(u0 << 16), acc.x);
      acc.y = fmaf(w0, __uint_as_float(u0 & 0xFFFF0000u), acc.y);
      acc.x = fmaf(w1, __uint_as_float(u1 << 16), acc.x);
      acc.y = fmaf(w1, __uint_as_float(u1 & 0xFFFF0000u), acc.y);
      acc.x = fmaf(w2, __uint_as_float(u2 << 16), acc.x);
      acc.y = fmaf(w2, __uint_as_float(u2 & 0xFFFF0000u), acc.y);
      acc.x = fmaf(w3, __uint_as_float(u3 << 16), acc.x);
      acc.y = fmaf(w3, __uint_as_float(u3 & 0xFFFF0000u), acc.y);
    }
    for (; e < e1; ++e) {
      int2 sw = csr[e];
      float w = __int_as_float(sw.y);
      unsigned int u = *(const unsigned int*)&S[(size_t)sw.x * DD + c0];
      acc.x = fmaf(w, __uint_as_float(u << 16), acc.x);
      acc.y = fmaf(w, __uint_as_float(u & 0xFFFF0000u), acc.y);
    }
    if (do_relu) { acc.x = fmaxf(acc.x, 0.f); acc.y = fmaxf(acc.y, 0.f); }
    if (Xout) {
      unsigned int xu = (unsigned int)f2bf(acc.x) | ((unsigned int)f2bf(acc.y) << 16);
      *(unsigned int*)&Xout[(size_t)d * DD + c0] = xu;
    }
    mx.x = fmaxf(mx.x, acc.x);
    mx.y = fmaxf(mx.y, acc.y);
  }
  atomicMax(&cmax[c0], fkey(mx.x));
  atomicMax(&cmax[c0 + 1], fkey(mx.y));
  __syncthreads();
  for (int i = threadIdx.x; i < DD; i += 256) atomicMax(&omax[i], cmax[i]);
}

// ---- head ----
__global__ void k_head(const unsigned int* __restrict__ omax,
                       const float* __restrict__ linW,
                       const float* __restrict__ linb,
                       float* __restrict__ out) {
  __shared__ float o[3 * DD];
  __shared__ float logits[NCLS];
  int t = threadIdx.x;  // block = 384
  if (t < 3 * DD) o[t] = funkey(omax[t]);
  __syncthreads();
  if (t < NCLS) {
    float acc = linb[t];
    for (int j = 0; j < 3 * DD; ++j) acc = fmaf(linW[t * 3 * DD + j], o[j], acc);
    logits[t] = acc;
  }
  __syncthreads();
  if (t == 0) {
    float m = -INFINITY;
    for (int c = 0; c < NCLS; ++c) m = fmaxf(m, logits[c]);
    float s = 0.f;
    for (int c = 0; c < NCLS; ++c) s += expf(logits[c] - m);
    float ls = logf(s);
    for (int c = 0; c < NCLS; ++c) out[c] = logits[c] - m - ls;
  }
}

extern "C" void kernel_launch(void* const* d_in, const int* in_sizes, int n_in,
                              void* d_out, int out_size, void* d_ws, size_t ws_size,
                              hipStream_t stream) {
  const float* x    = (const float*)d_in[0];
  const int*   esrc = (const int*)d_in[1];
  const int*   edst = (const int*)d_in[2];
  const float* ew   = (const float*)d_in[3];
  const float* W1   = (const float*)d_in[4];
  const float* b1   = (const float*)d_in[5];
  const float* W2   = (const float*)d_in[6];
  const float* b2   = (const float*)d_in[7];
  const float* W3   = (const float*)d_in[8];
  const float* b3   = (const float*)d_in[9];
  const float* linW = (const float*)d_in[10];
  const float* linb = (const float*)d_in[11];
  float* out = (float*)d_out;

  size_t off = 0;
  auto alloc = [&](size_t bytes) {
    void* p = (char*)d_ws + off;
    off += (bytes + 255) & ~(size_t)255;
    return p;
  };
  unsigned short* HB   = (unsigned short*)alloc((size_t)NPAD * DD * 2);  // x bf16 / X2
  unsigned short* XB   = (unsigned short*)alloc((size_t)NPAD * DD * 2);  // X1
  unsigned short* S    = (unsigned short*)alloc((size_t)NPAD * DD * 2);  // support
  unsigned short* WT1  = (unsigned short*)alloc((size_t)DD * DD * 2);
  unsigned short* WT2  = (unsigned short*)alloc((size_t)DD * DD * 2);
  unsigned short* WT3  = (unsigned short*)alloc((size_t)DD * DD * 2);
  int*          offs   = (int*)alloc((NN + 1) * 4);
  int*          cursor = (int*)alloc(NN * 4);
  int2*         csr    = (int2*)alloc((size_t)NE * 8);
  unsigned int* omax   = (unsigned int*)alloc(3 * DD * 4);
  int*          bsum   = (int*)alloc(NTILES * 4);
  (void)ws_size; (void)n_in; (void)in_sizes; (void)out_size;

  // CSR build (shared by all 3 layers)
  k_init<<<(NN + 256) / 256, 256, 0, stream>>>(offs, omax);
  k_count<<<(NE + 255) / 256, 256, 0, stream>>>(edst, offs);
  k_scan_partial<<<NTILES, SCAN_BLOCK, 0, stream>>>(offs, bsum);
  k_scan_bsum<<<1, 64, 0, stream>>>(bsum);
  k_scan_final<<<NTILES, SCAN_BLOCK, 0, stream>>>(offs, bsum, cursor);
  k_fill<<<(NE + 255) / 256, 256, 0, stream>>>(esrc, edst, ew, cursor, csr);

  // dtype prep
  k_cvt<<<2048, 256, 0, stream>>>(x, W1, W2, W3, HB, WT1, WT2, WT3);

  const int mm_grid = (NPAD / 64) * 2 / 4;  // 782 chunks x 2 col-halves / 4 waves = 391
  // layer 1
  k_mm<<<mm_grid, 256, 0, stream>>>(HB, WT1, S);
  k_agg<<<2048, 256, 0, stream>>>(S, csr, offs, b1, XB, omax, 1);
  // layer 2 (reuse HB as X2 buffer; x bf16 no longer needed)
  k_mm<<<mm_grid, 256, 0, stream>>>(XB, WT2, S);
  k_agg<<<2048, 256, 0, stream>>>(S, csr, offs, b2, HB, omax + DD, 1);
  // layer 3 (no X store, no relu)
  k_mm<<<mm_grid, 256, 0, stream>>>(HB, WT3, S);
  k_agg<<<2048, 256, 0, stream>>>(S, csr, offs, b3, nullptr, omax + 2 * DD, 0);

  k_head<<<1, 384, 0, stream>>>(omax, linW, linb, out);
}

// Round 3
// 438.581 us; speedup vs baseline: 1.3990x; 1.0045x over previous
//
#include <hip/hip_runtime.h>
#include <hip/hip_bf16.h>
#include <math.h>

#define NN 50000
#define NPAD 50048            // 1564 chunks of 32 rows
#define NE 800000
#define DD 128
#define NCLS 10
#define SCAN_BLOCK 1024
#define NTILES ((NN + 1 + SCAN_BLOCK - 1) / SCAN_BLOCK)  // 49

typedef short s16x8 __attribute__((ext_vector_type(8)));
typedef float f32x4 __attribute__((ext_vector_type(4)));

__device__ __forceinline__ unsigned short f2bf(float x) {
  __hip_bfloat16 h = __float2bfloat16(x);
  return __builtin_bit_cast(unsigned short, h);
}
__device__ __forceinline__ float bflo(unsigned int u) { return __uint_as_float(u << 16); }
__device__ __forceinline__ float bfhi(unsigned int u) { return __uint_as_float(u & 0xFFFF0000u); }

// ---- monotonic float<->uint key for atomic max over floats ----
__device__ __forceinline__ unsigned int fkey(float f) {
  unsigned int u = __float_as_uint(f);
  return u ^ ((u & 0x80000000u) ? 0xFFFFFFFFu : 0x80000000u);
}
__device__ __forceinline__ float funkey(unsigned int k) {
  unsigned int u = (k & 0x80000000u) ? (k ^ 0x80000000u) : ~k;
  return __uint_as_float(u);
}

// ---- init ----
__global__ void k_init(int* __restrict__ offs, unsigned int* __restrict__ omax) {
  int i = blockIdx.x * blockDim.x + threadIdx.x;
  if (i < NN + 1) offs[i] = 0;
  if (i < 3 * DD) omax[i] = 0u;
}

// ---- CSR build ----
__global__ void k_count(const int* __restrict__ edst, int* __restrict__ offs) {
  int e = blockIdx.x * blockDim.x + threadIdx.x;
  if (e < NE) atomicAdd(&offs[edst[e] + 1], 1);
}

__global__ void k_scan_partial(const int* __restrict__ offs, int* __restrict__ bsum) {
  __shared__ int red[SCAN_BLOCK];
  int i = blockIdx.x * SCAN_BLOCK + threadIdx.x;
  red[threadIdx.x] = (i < NN + 1) ? offs[i] : 0;
  __syncthreads();
  for (int off = SCAN_BLOCK / 2; off > 0; off >>= 1) {
    if ((int)threadIdx.x < off) red[threadIdx.x] += red[threadIdx.x + off];
    __syncthreads();
  }
  if (threadIdx.x == 0) bsum[blockIdx.x] = red[0];
}

__global__ void k_scan_bsum(int* __restrict__ bsum) {
  if (threadIdx.x == 0) {
    int run = 0;
    for (int i = 0; i < NTILES; ++i) { int v = bsum[i]; bsum[i] = run; run += v; }
  }
}

__global__ void k_scan_final(int* __restrict__ offs, const int* __restrict__ bsum,
                             int* __restrict__ cursor) {
  __shared__ int tmp[SCAN_BLOCK];
  int i = blockIdx.x * SCAN_BLOCK + threadIdx.x;
  int v = (i < NN + 1) ? offs[i] : 0;
  tmp[threadIdx.x] = v;
  __syncthreads();
  for (int off = 1; off < SCAN_BLOCK; off <<= 1) {
    int t = ((int)threadIdx.x >= off) ? tmp[threadIdx.x - off] : 0;
    __syncthreads();
    tmp[threadIdx.x] += t;
    __syncthreads();
  }
  int incl = tmp[threadIdx.x] + bsum[blockIdx.x];
  if (i < NN + 1) {
    offs[i] = incl;
    if (i < NN) cursor[i] = incl;
  }
}

__global__ void k_fill(const int* __restrict__ esrc, const int* __restrict__ edst,
                       const float* __restrict__ ew, int* __restrict__ cursor,
                       int2* __restrict__ csr) {
  int e = blockIdx.x * blockDim.x + threadIdx.x;
  if (e < NE) {
    int d = edst[e];
    int p = atomicAdd(&cursor[d], 1);
    csr[p] = make_int2(esrc[e], __float_as_int(ew[e]));
  }
}

// ---- convert W1..3 -> transposed bf16 WT[c][k] ----
__global__ __launch_bounds__(256) void k_cvtW(const float* __restrict__ W1,
    const float* __restrict__ W2, const float* __restrict__ W3,
    unsigned short* __restrict__ WT1, unsigned short* __restrict__ WT2,
    unsigned short* __restrict__ WT3) {
  int i = blockIdx.x * 256 + threadIdx.x;
  if (i < DD * DD) {
    int k = i >> 7, c = i & 127;
    WT1[c * DD + k] = f2bf(W1[i]);
    WT2[c * DD + k] = f2bf(W2[i]);
    WT3[c * DD + k] = f2bf(W3[i]);
  }
}

// ---- MFMA GEMM: S[r][c] = sum_k H[r][k] W[k][c]; 32 rows x 64 cols per wave ----
// S^T orientation: A = W^T frags, B = H frags -> C regs = 4 consecutive S cols.
template <int F32IN>
__global__ __launch_bounds__(256) void k_mm(const void* __restrict__ Hv,
                                            const unsigned short* __restrict__ Wt,
                                            unsigned short* __restrict__ S) {
  const int wave = threadIdx.x >> 6, lane = threadIdx.x & 63;
  const int gw = blockIdx.x * 4 + wave;           // 0 .. 3127
  const int r0 = (gw >> 1) * 32;
  const int cbase = (gw & 1) * 64;
  const int l15 = lane & 15, lk = (lane >> 4) * 8;

  s16x8 Af[4][4];  // [m = col-frag][ks]
#pragma unroll
  for (int m = 0; m < 4; ++m)
#pragma unroll
    for (int ks = 0; ks < 4; ++ks)
      Af[m][ks] = *(const s16x8*)&Wt[(cbase + m * 16 + l15) * DD + ks * 32 + lk];

  s16x8 Bf[2][4];  // [n = row-frag][ks]
#pragma unroll
  for (int n = 0; n < 2; ++n) {
    const int r = r0 + n * 16 + l15;
    if (F32IN) {
      const float* H = (const float*)Hv;
#pragma unroll
      for (int ks = 0; ks < 4; ++ks) {
        float4 a = make_float4(0.f, 0.f, 0.f, 0.f), b = a;
        if (r < NN) {
          a = *(const float4*)&H[(size_t)r * DD + ks * 32 + lk];
          b = *(const float4*)&H[(size_t)r * DD + ks * 32 + lk + 4];
        }
        s16x8 f;
        f[0] = (short)f2bf(a.x); f[1] = (short)f2bf(a.y);
        f[2] = (short)f2bf(a.z); f[3] = (short)f2bf(a.w);
        f[4] = (short)f2bf(b.x); f[5] = (short)f2bf(b.y);
        f[6] = (short)f2bf(b.z); f[7] = (short)f2bf(b.w);
        Bf[n][ks] = f;
      }
    } else {
      const unsigned short* H = (const unsigned short*)Hv;
#pragma unroll
      for (int ks = 0; ks < 4; ++ks)
        Bf[n][ks] = *(const s16x8*)&H[(size_t)r * DD + ks * 32 + lk];
    }
  }

  f32x4 acc[4][2];
#pragma unroll
  for (int m = 0; m < 4; ++m)
#pragma unroll
    for (int n = 0; n < 2; ++n) acc[m][n] = (f32x4){0.f, 0.f, 0.f, 0.f};

#pragma unroll
  for (int ks = 0; ks < 4; ++ks)
#pragma unroll
    for (int m = 0; m < 4; ++m)
#pragma unroll
      for (int n = 0; n < 2; ++n)
        acc[m][n] = __builtin_amdgcn_mfma_f32_16x16x32_bf16(Af[m][ks], Bf[n][ks],
                                                            acc[m][n], 0, 0, 0);

  const int csub = 4 * (lane >> 4);
#pragma unroll
  for (int m = 0; m < 4; ++m)
#pragma unroll
    for (int n = 0; n < 2; ++n) {
      uint2 pv;
      pv.x = (uint)f2bf(acc[m][n][0]) | ((uint)f2bf(acc[m][n][1]) << 16);
      pv.y = (uint)f2bf(acc[m][n][2]) | ((uint)f2bf(acc[m][n][3]) << 16);
      *(uint2*)&S[(size_t)(r0 + n * 16 + l15) * DD + cbase + m * 16 + csub] = pv;
    }
}

// ---- aggregation: quad-edge-parallel gather ----
// wave = 4 quads x 16 lanes; quad q owns edge slot q, lane t covers cols t*8..t*8+7.
__device__ __forceinline__ void fma8(float* acc, float w, uint4 u) {
  acc[0] = fmaf(w, bflo(u.x), acc[0]);
  acc[1] = fmaf(w, bfhi(u.x), acc[1]);
  acc[2] = fmaf(w, bflo(u.y), acc[2]);
  acc[3] = fmaf(w, bfhi(u.y), acc[3]);
  acc[4] = fmaf(w, bflo(u.z), acc[4]);
  acc[5] = fmaf(w, bfhi(u.z), acc[5]);
  acc[6] = fmaf(w, bflo(u.w), acc[6]);
  acc[7] = fmaf(w, bfhi(u.w), acc[7]);
}

__global__ __launch_bounds__(256) void k_agg(const unsigned short* __restrict__ S,
                                             const int2* __restrict__ csr,
                                             const int* __restrict__ offs,
                                             const float* __restrict__ bias,
                                             unsigned short* __restrict__ Xout,  // may be null
                                             unsigned int* __restrict__ omax,
                                             int do_relu) {
  __shared__ unsigned int cmax[DD];
  for (int i = threadIdx.x; i < DD; i += 256) cmax[i] = 0u;
  __syncthreads();
  const int lane = threadIdx.x & 63;
  const int wave = threadIdx.x >> 6;
  const int q = lane >> 4;
  const int t = lane & 15;
  const int gwave = blockIdx.x * 4 + wave;
  const int nwaves = gridDim.x * 4;

  float bcol[8];
  {
    float4 b0 = *(const float4*)&bias[t * 8];
    float4 b1 = *(const float4*)&bias[t * 8 + 4];
    bcol[0] = b0.x; bcol[1] = b0.y; bcol[2] = b0.z; bcol[3] = b0.w;
    bcol[4] = b1.x; bcol[5] = b1.y; bcol[6] = b1.z; bcol[7] = b1.w;
  }
  float mx[8];
#pragma unroll
  for (int j = 0; j < 8; ++j) mx[j] = -INFINITY;

  for (int d = gwave; d < NN; d += nwaves) {
    const int e0 = offs[d], e1 = offs[d + 1];
    float acc[8] = {0.f, 0.f, 0.f, 0.f, 0.f, 0.f, 0.f, 0.f};
    int e = e0 + q;
    const int nfull = (e1 - e0) >> 4;
    for (int s = 0; s < nfull; ++s, e += 16) {
      int2 c0 = csr[e];
      int2 c1 = csr[e + 4];
      int2 c2 = csr[e + 8];
      int2 c3 = csr[e + 12];
      uint4 u0 = *(const uint4*)&S[(size_t)c0.x * DD + t * 8];
      uint4 u1 = *(const uint4*)&S[(size_t)c1.x * DD + t * 8];
      uint4 u2 = *(const uint4*)&S[(size_t)c2.x * DD + t * 8];
      uint4 u3 = *(const uint4*)&S[(size_t)c3.x * DD + t * 8];
      fma8(acc, __int_as_float(c0.y), u0);
      fma8(acc, __int_as_float(c1.y), u1);
      fma8(acc, __int_as_float(c2.y), u2);
      fma8(acc, __int_as_float(c3.y), u3);
    }
    while (__any(e < e1)) {
      if (e < e1) {
        int2 c = csr[e];
        uint4 u = *(const uint4*)&S[(size_t)c.x * DD + t * 8];
        fma8(acc, __int_as_float(c.y), u);
      }
      e += 4;
    }
    // cross-quad butterfly reduce + finalize
#pragma unroll
    for (int j = 0; j < 8; ++j) {
      acc[j] += __shfl_xor(acc[j], 16, 64);
      acc[j] += __shfl_xor(acc[j], 32, 64);
      acc[j] += bcol[j];
      if (do_relu) acc[j] = fmaxf(acc[j], 0.f);
      mx[j] = fmaxf(mx[j], acc[j]);
    }
    if (Xout && q == 0) {
      uint4 xv;
      xv.x = (uint)f2bf(acc[0]) | ((uint)f2bf(acc[1]) << 16);
      xv.y = (uint)f2bf(acc[2]) | ((uint)f2bf(acc[3]) << 16);
      xv.z = (uint)f2bf(acc[4]) | ((uint)f2bf(acc[5]) << 16);
      xv.w = (uint)f2bf(acc[6]) | ((uint)f2bf(acc[7]) << 16);
      *(uint4*)&Xout[(size_t)d * DD + t * 8] = xv;
    }
  }
  if (q == 0) {
#pragma unroll
    for (int j = 0; j < 8; ++j) atomicMax(&cmax[t * 8 + j], fkey(mx[j]));
  }
  __syncthreads();
  for (int i = threadIdx.x; i < DD; i += 256) atomicMax(&omax[i], cmax[i]);
}

// ---- head ----
__global__ void k_head(const unsigned int* __restrict__ omax,
                       const float* __restrict__ linW,
                       const float* __restrict__ linb,
                       float* __restrict__ out) {
  __shared__ float o[3 * DD];
  __shared__ float logits[NCLS];
  int t = threadIdx.x;  // block = 384
  if (t < 3 * DD) o[t] = funkey(omax[t]);
  __syncthreads();
  if (t < NCLS) {
    float acc = linb[t];
    for (int j = 0; j < 3 * DD; ++j) acc = fmaf(linW[t * 3 * DD + j], o[j], acc);
    logits[t] = acc;
  }
  __syncthreads();
  if (t == 0) {
    float m = -INFINITY;
    for (int c = 0; c < NCLS; ++c) m = fmaxf(m, logits[c]);
    float s = 0.f;
    for (int c = 0; c < NCLS; ++c) s += expf(logits[c] - m);
    float ls = logf(s);
    for (int c = 0; c < NCLS; ++c) out[c] = logits[c] - m - ls;
  }
}

extern "C" void kernel_launch(void* const* d_in, const int* in_sizes, int n_in,
                              void* d_out, int out_size, void* d_ws, size_t ws_size,
                              hipStream_t stream) {
  const float* x    = (const float*)d_in[0];
  const int*   esrc = (const int*)d_in[1];
  const int*   edst = (const int*)d_in[2];
  const float* ew   = (const float*)d_in[3];
  const float* W1   = (const float*)d_in[4];
  const float* b1   = (const float*)d_in[5];
  const float* W2   = (const float*)d_in[6];
  const float* b2   = (const float*)d_in[7];
  const float* W3   = (const float*)d_in[8];
  const float* b3   = (const float*)d_in[9];
  const float* linW = (const float*)d_in[10];
  const float* linb = (const float*)d_in[11];
  float* out = (float*)d_out;

  size_t off = 0;
  auto alloc = [&](size_t bytes) {
    void* p = (char*)d_ws + off;
    off += (bytes + 255) & ~(size_t)255;
    return p;
  };
  unsigned short* X1   = (unsigned short*)alloc((size_t)NPAD * DD * 2);
  unsigned short* X2   = (unsigned short*)alloc((size_t)NPAD * DD * 2);
  unsigned short* S    = (unsigned short*)alloc((size_t)NPAD * DD * 2);
  unsigned short* WT1  = (unsigned short*)alloc((size_t)DD * DD * 2);
  unsigned short* WT2  = (unsigned short*)alloc((size_t)DD * DD * 2);
  unsigned short* WT3  = (unsigned short*)alloc((size_t)DD * DD * 2);
  int*          offs   = (int*)alloc((NN + 1) * 4);
  int*          cursor = (int*)alloc(NN * 4);
  int2*         csr    = (int2*)alloc((size_t)NE * 8);
  unsigned int* omax   = (unsigned int*)alloc(3 * DD * 4);
  int*          bsum   = (int*)alloc(NTILES * 4);
  (void)ws_size; (void)n_in; (void)in_sizes; (void)out_size;

  // CSR build (shared by all 3 layers)
  k_init<<<(NN + 256) / 256, 256, 0, stream>>>(offs, omax);
  k_count<<<(NE + 255) / 256, 256, 0, stream>>>(edst, offs);
  k_scan_partial<<<NTILES, SCAN_BLOCK, 0, stream>>>(offs, bsum);
  k_scan_bsum<<<1, 64, 0, stream>>>(bsum);
  k_scan_final<<<NTILES, SCAN_BLOCK, 0, stream>>>(offs, bsum, cursor);
  k_fill<<<(NE + 255) / 256, 256, 0, stream>>>(esrc, edst, ew, cursor, csr);

  k_cvtW<<<(DD * DD + 255) / 256, 256, 0, stream>>>(W1, W2, W3, WT1, WT2, WT3);

  const int mm_grid = (NPAD / 32) * 2 / 4;  // 782
  // layer 1 (fp32 x read + convert fused into GEMM)
  k_mm<1><<<mm_grid, 256, 0, stream>>>(x, WT1, S);
  k_agg<<<2048, 256, 0, stream>>>(S, csr, offs, b1, X1, omax, 1);
  // layer 2
  k_mm<0><<<mm_grid, 256, 0, stream>>>(X1, WT2, S);
  k_agg<<<2048, 256, 0, stream>>>(S, csr, offs, b2, X2, omax + DD, 1);
  // layer 3 (no X store, no relu)
  k_mm<0><<<mm_grid, 256, 0, stream>>>(X2, WT3, S);
  k_agg<<<2048, 256, 0, stream>>>(S, csr, offs, b3, nullptr, omax + 2 * DD, 0);

  k_head<<<1, 384, 0, stream>>>(omax, linW, linb, out);
}

// Round 5
// 429.109 us; speedup vs baseline: 1.4298x; 1.0221x over previous
//
#include <hip/hip_runtime.h>
#include <hip/hip_bf16.h>
#include <math.h>

#define NN 50000
#define NPAD 50048            // 1564 chunks of 32 rows
#define NE 800000
#define DD 128
#define NCLS 10
#define SCAN_BLOCK 1024
#define NTILES ((NN + 1 + SCAN_BLOCK - 1) / SCAN_BLOCK)  // 49

typedef short s16x8 __attribute__((ext_vector_type(8)));
typedef float f32x4 __attribute__((ext_vector_type(4)));

__device__ __forceinline__ unsigned short f2bf(float x) {
  __hip_bfloat16 h = __float2bfloat16(x);
  return __builtin_bit_cast(unsigned short, h);
}
__device__ __forceinline__ float bflo(unsigned int u) { return __uint_as_float(u << 16); }
__device__ __forceinline__ float bfhi(unsigned int u) { return __uint_as_float(u & 0xFFFF0000u); }

// ---- monotonic float<->uint key for atomic max over floats ----
__device__ __forceinline__ unsigned int fkey(float f) {
  unsigned int u = __float_as_uint(f);
  return u ^ ((u & 0x80000000u) ? 0xFFFFFFFFu : 0x80000000u);
}
__device__ __forceinline__ float funkey(unsigned int k) {
  unsigned int u = (k & 0x80000000u) ? (k ^ 0x80000000u) : ~k;
  return __uint_as_float(u);
}

// ---- init ----
__global__ void k_init(int* __restrict__ offs, unsigned int* __restrict__ omax) {
  int i = blockIdx.x * blockDim.x + threadIdx.x;
  if (i < NN + 1) offs[i] = 0;
  if (i < 3 * DD) omax[i] = 0u;
}

// ---- CSR build ----
__global__ void k_count(const int* __restrict__ edst, int* __restrict__ offs) {
  int e = blockIdx.x * blockDim.x + threadIdx.x;
  if (e < NE) atomicAdd(&offs[edst[e] + 1], 1);
}

__global__ void k_scan_partial(const int* __restrict__ offs, int* __restrict__ bsum) {
  __shared__ int red[SCAN_BLOCK];
  int i = blockIdx.x * SCAN_BLOCK + threadIdx.x;
  red[threadIdx.x] = (i < NN + 1) ? offs[i] : 0;
  __syncthreads();
  for (int off = SCAN_BLOCK / 2; off > 0; off >>= 1) {
    if ((int)threadIdx.x < off) red[threadIdx.x] += red[threadIdx.x + off];
    __syncthreads();
  }
  if (threadIdx.x == 0) bsum[blockIdx.x] = red[0];
}

__global__ void k_scan_bsum(int* __restrict__ bsum) {
  if (threadIdx.x == 0) {
    int run = 0;
    for (int i = 0; i < NTILES; ++i) { int v = bsum[i]; bsum[i] = run; run += v; }
  }
}

__global__ void k_scan_final(int* __restrict__ offs, const int* __restrict__ bsum,
                             int* __restrict__ cursor) {
  __shared__ int tmp[SCAN_BLOCK];
  int i = blockIdx.x * SCAN_BLOCK + threadIdx.x;
  int v = (i < NN + 1) ? offs[i] : 0;
  tmp[threadIdx.x] = v;
  __syncthreads();
  for (int off = 1; off < SCAN_BLOCK; off <<= 1) {
    int t = ((int)threadIdx.x >= off) ? tmp[threadIdx.x - off] : 0;
    __syncthreads();
    tmp[threadIdx.x] += t;
    __syncthreads();
  }
  int incl = tmp[threadIdx.x] + bsum[blockIdx.x];
  if (i < NN + 1) {
    offs[i] = incl;
    if (i < NN) cursor[i] = incl;
  }
}

__global__ void k_fill(const int* __restrict__ esrc, const int* __restrict__ edst,
                       const float* __restrict__ ew, int* __restrict__ cursor,
                       int2* __restrict__ csr) {
  int e = blockIdx.x * blockDim.x + threadIdx.x;
  if (e < NE) {
    int d = edst[e];
    int p = atomicAdd(&cursor[d], 1);
    csr[p] = make_int2(esrc[e], __float_as_int(ew[e]));
  }
}

// ---- convert W1..3 -> transposed bf16 WT[c][k] ----
__global__ __launch_bounds__(256) void k_cvtW(const float* __restrict__ W1,
    const float* __restrict__ W2, const float* __restrict__ W3,
    unsigned short* __restrict__ WT1, unsigned short* __restrict__ WT2,
    unsigned short* __restrict__ WT3) {
  int i = blockIdx.x * 256 + threadIdx.x;
  if (i < DD * DD) {
    int k = i >> 7, c = i & 127;
    WT1[c * DD + k] = f2bf(W1[i]);
    WT2[c * DD + k] = f2bf(W2[i]);
    WT3[c * DD + k] = f2bf(W3[i]);
  }
}

// ---- MFMA GEMM, LDS-staged: S[r][c] = sum_k H[r][k] W[k][c] ----
// block = 256 thr (4 waves), tile = 32 rows x 128 cols. grid = NPAD/32.
// LDS tile swizzled: 16B granule at byte B stored at B ^ ((row&7)<<4).
// S^T orientation: A = W^T frags (global, L1-hot), B = H frags (LDS).
template <int F32IN>
__global__ __launch_bounds__(256) void k_mm(const void* __restrict__ Hv,
                                            const unsigned short* __restrict__ Wt,
                                            unsigned short* __restrict__ S) {
  __shared__ unsigned short Hl[32 * DD];   // 8 KB, byte-addressed below
  char* lb = (char*)Hl;
  const int wave = threadIdx.x >> 6, lane = threadIdx.x & 63;
  const int l15 = lane & 15, lk16 = (lane >> 4);   // lk = lk16*8 elems
  const int r0 = blockIdx.x * 32;

  // ---- load 32x128 bf16 tile into LDS, coalesced, swizzled ----
#pragma unroll
  for (int j = 0; j < 2; ++j) {
    const int idx = threadIdx.x + j * 256;     // 0..511 granules of 16B
    const int B = idx * 16;
    const int row = B >> 8;
    const int addr = B ^ ((row & 7) << 4);
    if (F32IN) {
      const float* H = (const float*)Hv;
      const int r = r0 + row;
      float4 a = make_float4(0.f, 0.f, 0.f, 0.f), b = a;
      if (r < NN) {
        const float* src = H + (size_t)r * DD + ((B & 255) >> 1);
        a = *(const float4*)src;
        b = *(const float4*)(src + 4);
      }
      uint4 pv;
      pv.x = (uint)f2bf(a.x) | ((uint)f2bf(a.y) << 16);
      pv.y = (uint)f2bf(a.z) | ((uint)f2bf(a.w) << 16);
      pv.z = (uint)f2bf(b.x) | ((uint)f2bf(b.y) << 16);
      pv.w = (uint)f2bf(b.z) | ((uint)f2bf(b.w) << 16);
      *(uint4*)(lb + addr) = pv;
    } else {
      const char* H = (const char*)Hv;
      uint4 v = *(const uint4*)(H + (size_t)r0 * 256 + B);
      *(uint4*)(lb + addr) = v;
    }
  }
  __syncthreads();

  // ---- fragments ----
  const int cbase = wave * 32;
  s16x8 Af[2][4];
#pragma unroll
  for (int m = 0; m < 2; ++m)
#pragma unroll
    for (int ks = 0; ks < 4; ++ks)
      Af[m][ks] = *(const s16x8*)&Wt[(cbase + m * 16 + l15) * DD + ks * 32 + lk16 * 8];

  s16x8 Bf[2][4];
#pragma unroll
  for (int n = 0; n < 2; ++n) {
    const int row = n * 16 + l15;
#pragma unroll
    for (int ks = 0; ks < 4; ++ks) {
      const int B = row * 256 + ks * 64 + lk16 * 16;
      Bf[n][ks] = *(const s16x8*)(lb + (B ^ ((row & 7) << 4)));
    }
  }

  f32x4 acc[2][2];
#pragma unroll
  for (int m = 0; m < 2; ++m)
#pragma unroll
    for (int n = 0; n < 2; ++n) acc[m][n] = (f32x4){0.f, 0.f, 0.f, 0.f};

#pragma unroll
  for (int ks = 0; ks < 4; ++ks)
#pragma unroll
    for (int m = 0; m < 2; ++m)
#pragma unroll
      for (int n = 0; n < 2; ++n)
        acc[m][n] = __builtin_amdgcn_mfma_f32_16x16x32_bf16(Af[m][ks], Bf[n][ks],
                                                            acc[m][n], 0, 0, 0);

  // ---- stage output tile through LDS (reuse Hl), then linear stores ----
  __syncthreads();
#pragma unroll
  for (int m = 0; m < 2; ++m)
#pragma unroll
    for (int n = 0; n < 2; ++n) {
      const int row = n * 16 + l15;
      const int colb = (cbase + m * 16 + 4 * lk16) * 2;
      const int B = row * 256 + colb;
      uint2 pv;
      pv.x = (uint)f2bf(acc[m][n][0]) | ((uint)f2bf(acc[m][n][1]) << 16);
      pv.y = (uint)f2bf(acc[m][n][2]) | ((uint)f2bf(acc[m][n][3]) << 16);
      *(uint2*)(lb + (B ^ ((row & 7) << 4))) = pv;
    }
  __syncthreads();
#pragma unroll
  for (int j = 0; j < 2; ++j) {
    const int idx = threadIdx.x + j * 256;
    const int B = idx * 16;
    const int row = B >> 8;
    uint4 v = *(const uint4*)(lb + (B ^ ((row & 7) << 4)));
    *(uint4*)((char*)S + (size_t)r0 * 256 + B) = v;
  }
}

// ---- aggregation: quad-edge-parallel gather, 2 supersteps in flight ----
__device__ __forceinline__ void fma8(float* acc, float w, uint4 u) {
  acc[0] = fmaf(w, bflo(u.x), acc[0]);
  acc[1] = fmaf(w, bfhi(u.x), acc[1]);
  acc[2] = fmaf(w, bflo(u.y), acc[2]);
  acc[3] = fmaf(w, bfhi(u.y), acc[3]);
  acc[4] = fmaf(w, bflo(u.z), acc[4]);
  acc[5] = fmaf(w, bfhi(u.z), acc[5]);
  acc[6] = fmaf(w, bflo(u.w), acc[6]);
  acc[7] = fmaf(w, bfhi(u.w), acc[7]);
}

__global__ __launch_bounds__(256) void k_agg(const unsigned short* __restrict__ S,
                                             const int2* __restrict__ csr,
                                             const int* __restrict__ offs,
                                             const float* __restrict__ bias,
                                             unsigned short* __restrict__ Xout,  // may be null
                                             unsigned int* __restrict__ omax,
                                             int do_relu) {
  __shared__ unsigned int cmax[DD];
  for (int i = threadIdx.x; i < DD; i += 256) cmax[i] = 0u;
  __syncthreads();
  const int lane = threadIdx.x & 63;
  const int wave = threadIdx.x >> 6;
  const int q = lane >> 4;
  const int t = lane & 15;
  const int gwave = blockIdx.x * 4 + wave;
  const int nwaves = gridDim.x * 4;
  const unsigned short* Scol = S + t * 8;

  float bcol[8];
  {
    float4 b0 = *(const float4*)&bias[t * 8];
    float4 b1 = *(const float4*)&bias[t * 8 + 4];
    bcol[0] = b0.x; bcol[1] = b0.y; bcol[2] = b0.z; bcol[3] = b0.w;
    bcol[4] = b1.x; bcol[5] = b1.y; bcol[6] = b1.z; bcol[7] = b1.w;
  }
  float mx[8];
#pragma unroll
  for (int j = 0; j < 8; ++j) mx[j] = -INFINITY;

  for (int d = gwave; d < NN; d += nwaves) {
    const int e0 = offs[d], e1 = offs[d + 1];
    const int nedge = e1 - e0;
    float acc[8] = {0.f, 0.f, 0.f, 0.f, 0.f, 0.f, 0.f, 0.f};
    int e = e0 + q;
    int done = 0;
    for (; done + 32 <= nedge; done += 32, e += 32) {
      int2 a0 = csr[e];      int2 a1 = csr[e + 4];
      int2 a2 = csr[e + 8];  int2 a3 = csr[e + 12];
      int2 a4 = csr[e + 16]; int2 a5 = csr[e + 20];
      int2 a6 = csr[e + 24]; int2 a7 = csr[e + 28];
      uint4 u0 = *(const uint4*)&Scol[(size_t)a0.x * DD];
      uint4 u1 = *(const uint4*)&Scol[(size_t)a1.x * DD];
      uint4 u2 = *(const uint4*)&Scol[(size_t)a2.x * DD];
      uint4 u3 = *(const uint4*)&Scol[(size_t)a3.x * DD];
      uint4 u4 = *(const uint4*)&Scol[(size_t)a4.x * DD];
      uint4 u5 = *(const uint4*)&Scol[(size_t)a5.x * DD];
      uint4 u6 = *(const uint4*)&Scol[(size_t)a6.x * DD];
      uint4 u7 = *(const uint4*)&Scol[(size_t)a7.x * DD];
      fma8(acc, __int_as_float(a0.y), u0);
      fma8(acc, __int_as_float(a1.y), u1);
      fma8(acc, __int_as_float(a2.y), u2);
      fma8(acc, __int_as_float(a3.y), u3);
      fma8(acc, __int_as_float(a4.y), u4);
      fma8(acc, __int_as_float(a5.y), u5);
      fma8(acc, __int_as_float(a6.y), u6);
      fma8(acc, __int_as_float(a7.y), u7);
    }
    if (done + 16 <= nedge) {
      int2 a0 = csr[e];      int2 a1 = csr[e + 4];
      int2 a2 = csr[e + 8];  int2 a3 = csr[e + 12];
      uint4 u0 = *(const uint4*)&Scol[(size_t)a0.x * DD];
      uint4 u1 = *(const uint4*)&Scol[(size_t)a1.x * DD];
      uint4 u2 = *(const uint4*)&Scol[(size_t)a2.x * DD];
      uint4 u3 = *(const uint4*)&Scol[(size_t)a3.x * DD];
      fma8(acc, __int_as_float(a0.y), u0);
      fma8(acc, __int_as_float(a1.y), u1);
      fma8(acc, __int_as_float(a2.y), u2);
      fma8(acc, __int_as_float(a3.y), u3);
      done += 16; e += 16;
    }
    while (__any(e < e1)) {
      if (e < e1) {
        int2 c = csr[e];
        uint4 u = *(const uint4*)&Scol[(size_t)c.x * DD];
        fma8(acc, __int_as_float(c.y), u);
      }
      e += 4;
    }
    // cross-quad butterfly reduce + finalize
#pragma unroll
    for (int j = 0; j < 8; ++j) {
      acc[j] += __shfl_xor(acc[j], 16, 64);
      acc[j] += __shfl_xor(acc[j], 32, 64);
      acc[j] += bcol[j];
      if (do_relu) acc[j] = fmaxf(acc[j], 0.f);
      mx[j] = fmaxf(mx[j], acc[j]);
    }
    if (Xout && q == 0) {
      uint4 xv;
      xv.x = (uint)f2bf(acc[0]) | ((uint)f2bf(acc[1]) << 16);
      xv.y = (uint)f2bf(acc[2]) | ((uint)f2bf(acc[3]) << 16);
      xv.z = (uint)f2bf(acc[4]) | ((uint)f2bf(acc[5]) << 16);
      xv.w = (uint)f2bf(acc[6]) | ((uint)f2bf(acc[7]) << 16);
      *(uint4*)&Xout[(size_t)d * DD + t * 8] = xv;
    }
  }
  if (q == 0) {
#pragma unroll
    for (int j = 0; j < 8; ++j) atomicMax(&cmax[t * 8 + j], fkey(mx[j]));
  }
  __syncthreads();
  for (int i = threadIdx.x; i < DD; i += 256) atomicMax(&omax[i], cmax[i]);
}

// ---- head ----
__global__ void k_head(const unsigned int* __restrict__ omax,
                       const float* __restrict__ linW,
                       const float* __restrict__ linb,
                       float* __restrict__ out) {
  __shared__ float o[3 * DD];
  __shared__ float logits[NCLS];
  int t = threadIdx.x;  // block = 384
  if (t < 3 * DD) o[t] = funkey(omax[t]);
  __syncthreads();
  if (t < NCLS) {
    float acc = linb[t];
    for (int j = 0; j < 3 * DD; ++j) acc = fmaf(linW[t * 3 * DD + j], o[j], acc);
    logits[t] = acc;
  }
  __syncthreads();
  if (t == 0) {
    float m = -INFINITY;
    for (int c = 0; c < NCLS; ++c) m = fmaxf(m, logits[c]);
    float s = 0.f;
    for (int c = 0; c < NCLS; ++c) s += expf(logits[c] - m);
    float ls = logf(s);
    for (int c = 0; c < NCLS; ++c) out[c] = logits[c] - m - ls;
  }
}

extern "C" void kernel_launch(void* const* d_in, const int* in_sizes, int n_in,
                              void* d_out, int out_size, void* d_ws, size_t ws_size,
                              hipStream_t stream) {
  const float* x    = (const float*)d_in[0];
  const int*   esrc = (const int*)d_in[1];
  const int*   edst = (const int*)d_in[2];
  const float* ew   = (const float*)d_in[3];
  const float* W1   = (const float*)d_in[4];
  const float* b1   = (const float*)d_in[5];
  const float* W2   = (const float*)d_in[6];
  const float* b2   = (const float*)d_in[7];
  const float* W3   = (const float*)d_in[8];
  const float* b3   = (const float*)d_in[9];
  const float* linW = (const float*)d_in[10];
  const float* linb = (const float*)d_in[11];
  float* out = (float*)d_out;

  size_t off = 0;
  auto alloc = [&](size_t bytes) {
    void* p = (char*)d_ws + off;
    off += (bytes + 255) & ~(size_t)255;
    return p;
  };
  unsigned short* X1   = (unsigned short*)alloc((size_t)NPAD * DD * 2);
  unsigned short* X2   = (unsigned short*)alloc((size_t)NPAD * DD * 2);
  unsigned short* S    = (unsigned short*)alloc((size_t)NPAD * DD * 2);
  unsigned short* WT1  = (unsigned short*)alloc((size_t)DD * DD * 2);
  unsigned short* WT2  = (unsigned short*)alloc((size_t)DD * DD * 2);
  unsigned short* WT3  = (unsigned short*)alloc((size_t)DD * DD * 2);
  int*          offs   = (int*)alloc((NN + 1) * 4);
  int*          cursor = (int*)alloc(NN * 4);
  int2*         csr    = (int2*)alloc((size_t)NE * 8);
  unsigned int* omax   = (unsigned int*)alloc(3 * DD * 4);
  int*          bsum   = (int*)alloc(NTILES * 4);
  (void)ws_size; (void)n_in; (void)in_sizes; (void)out_size;

  // CSR build (shared by all 3 layers)
  k_init<<<(NN + 256) / 256, 256, 0, stream>>>(offs, omax);
  k_count<<<(NE + 255) / 256, 256, 0, stream>>>(edst, offs);
  k_scan_partial<<<NTILES, SCAN_BLOCK, 0, stream>>>(offs, bsum);
  k_scan_bsum<<<1, 64, 0, stream>>>(bsum);
  k_scan_final<<<NTILES, SCAN_BLOCK, 0, stream>>>(offs, bsum, cursor);
  k_fill<<<(NE + 255) / 256, 256, 0, stream>>>(esrc, edst, ew, cursor, csr);

  k_cvtW<<<(DD * DD + 255) / 256, 256, 0, stream>>>(W1, W2, W3, WT1, WT2, WT3);

  const int mm_grid = NPAD / 32;  // 1564
  // layer 1 (fp32 x read + convert fused into GEMM staging)
  k_mm<1><<<mm_grid, 256, 0, stream>>>(x, WT1, S);
  k_agg<<<2048, 256, 0, stream>>>(S, csr, offs, b1, X1, omax, 1);
  // layer 2
  k_mm<0><<<mm_grid, 256, 0, stream>>>(X1, WT2, S);
  k_agg<<<2048, 256, 0, stream>>>(S, csr, offs, b2, X2, omax + DD, 1);
  // layer 3 (no X store, no relu)
  k_mm<0><<<mm_grid, 256, 0, stream>>>(X2, WT3, S);
  k_agg<<<2048, 256, 0, stream>>>(S, csr, offs, b3, nullptr, omax + 2 * DD, 0);

  k_head<<<1, 384, 0, stream>>>(omax, linW, linb, out);
}